// Round 3
// baseline (544.110 us; speedup 1.0000x reference)
//
#include <hip/hip_runtime.h>

#define B_TOT 8192
#define T_OBS 128
#define T_FUT 64
#define T_ALL 192
#define DIN 5
#define HD 128
#define BT 16          // batch rows per block (one 16-row MFMA A-tile)
#define LDSTR 136      // Abuf row stride in shorts (pad 8)

typedef __attribute__((ext_vector_type(8))) short short8;
typedef __attribute__((ext_vector_type(4))) float f32x4;

__device__ inline short f2bf(float f) {
    unsigned u = __float_as_uint(f);
    u += 0x7FFFu + ((u >> 16) & 1u);   // round-to-nearest-even
    return (short)(u >> 16);
}

__device__ inline float sigm(float x) {
    return __builtin_amdgcn_rcpf(1.f + __expf(-x));
}
__device__ inline float tanh_(float x) {
    return 1.f - 2.f * __builtin_amdgcn_rcpf(1.f + __expf(2.f * x));
}

__device__ inline f32x4 MFMA(short8 a, short8 b, f32x4 c) {
    return __builtin_amdgcn_mfma_f32_16x16x32_bf16(a, b, c, 0, 0, 0);
}

__device__ inline short8 load_w8(const float* p) {
    float4 a = *reinterpret_cast<const float4*>(p);
    float4 b = *reinterpret_cast<const float4*>(p + 4);
    short8 r;
    r[0] = f2bf(a.x); r[1] = f2bf(a.y); r[2] = f2bf(a.z); r[3] = f2bf(a.w);
    r[4] = f2bf(b.x); r[5] = f2bf(b.y); r[6] = f2bf(b.z); r[7] = f2bf(b.w);
    return r;
}
__device__ inline short8 load_w5(const float* p) {
    short8 r = (short8)0;
    r[0] = f2bf(p[0]); r[1] = f2bf(p[1]); r[2] = f2bf(p[2]);
    r[3] = f2bf(p[3]); r[4] = f2bf(p[4]);
    return r;
}

// 512 threads = 8 waves; wave w owns gate-columns [16w,16w+16) of r/z/n.
// Block owns 16 batch rows; grid = 512 blocks = 2 blocks/CU = 4 waves/SIMD,
// so one block's barrier stall is hidden by the other block's waves.
// Weights: 15 short8 = 60 VGPR/lane. Head weights + all x inputs staged in
// LDS to keep VGPR <= 128 and to delete per-step global loads / cvt.
__global__ __launch_bounds__(512, 4)
void gru_tracemodel_kernel(const float* __restrict__ obs, const float* __restrict__ target,
                           const float* __restrict__ eWih, const float* __restrict__ eWhh,
                           const float* __restrict__ ebih, const float* __restrict__ ebhh,
                           const float* __restrict__ cWih, const float* __restrict__ cWhh,
                           const float* __restrict__ cbih, const float* __restrict__ cbhh,
                           const float* __restrict__ headW, const float* __restrict__ headb,
                           float* __restrict__ out)
{
    __shared__ __attribute__((aligned(16))) short Abuf[2][BT][LDSTR];   // 8.5 KB
    __shared__ __attribute__((aligned(16))) short Xbuf[T_ALL][BT][8];   // 48 KB
    __shared__ __attribute__((aligned(16))) short HeadLds[4][64][8];    // 4 KB

    const int tid   = threadIdx.x;
    const int wave  = tid >> 6;    // 0..7
    const int lane  = tid & 63;
    const int q     = lane >> 4;   // quad (A/B k-group, C/D row-group)
    const int c     = lane & 15;   // col-in-tile / A row
    const int b0    = blockIdx.x * BT;
    const int wbase = wave * 16;   // this wave's gate-column slice

    // h0 = 0 (only buffer 0 needed)
    for (int i = tid; i < BT * LDSTR; i += 512) ((short*)Abuf)[i] = 0;

    // stage all x_t as zero-padded bf16 A-rows: Xbuf[t][row][0..4]=x, [5..7]=0
    for (int i = tid; i < T_ALL * BT; i += 512) {
        const int t = i % T_ALL;          // t fastest -> near-coalesced loads
        const int r = i / T_ALL;
        const float* src;
        if (t < T_OBS)       src = obs    + ((size_t)(b0 + r) * T_OBS + t) * DIN;
        else if (t == T_OBS) src = obs    + ((size_t)(b0 + r) * T_OBS + (T_OBS - 1)) * DIN;
        else                 src = target + ((size_t)(b0 + r) * T_FUT + (t - T_OBS - 1)) * DIN;
        short* dst = &Xbuf[t][r][0];
        #pragma unroll
        for (int j = 0; j < DIN; ++j) dst[j] = f2bf(src[j]);
        dst[5] = 0; dst[6] = 0; dst[7] = 0;
    }

    // ---- weight fragments (B-operand: lane holds W'[n][k = kt*32+q*8+j]) ----
    short8 Wr[5], Wz[5], Wn[5];
    float  br, bz, bnh_, bni_;

    auto load_phase = [&](const float* Wih, const float* Whh,
                          const float* bih, const float* bhh) {
        const int nr = 0 * HD + wbase + c;
        const int nz = 1 * HD + wbase + c;
        const int nn = 2 * HD + wbase + c;
        #pragma unroll
        for (int kt = 0; kt < 4; ++kt) {
            Wr[kt] = load_w8(Whh + nr * HD + kt * 32 + q * 8);
            Wz[kt] = load_w8(Whh + nz * HD + kt * 32 + q * 8);
            Wn[kt] = load_w8(Whh + nn * HD + kt * 32 + q * 8);
        }
        Wr[4] = (q == 0) ? load_w5(Wih + nr * DIN) : (short8)0;
        Wz[4] = (q == 0) ? load_w5(Wih + nz * DIN) : (short8)0;
        Wn[4] = (q == 0) ? load_w5(Wih + nn * DIN) : (short8)0;
        br   = bih[nr] + bhh[nr];
        bz   = bih[nz] + bhh[nz];
        bnh_ = bhh[nn];
        bni_ = bih[nn];
    };
    load_phase(eWih, eWhh, ebih, ebhh);

    // head B-fragments into LDS (wave 0 only reads them back)
    float hb = 0.f;
    if (wave == 0) {
        #pragma unroll
        for (int kt = 0; kt < 4; ++kt) {
            short8 w = (c < DIN) ? load_w8(headW + c * HD + kt * 32 + q * 8) : (short8)0;
            *reinterpret_cast<short8*>(&HeadLds[kt][lane][0]) = w;
        }
        hb = (c < DIN) ? headb[c] : 0.f;
    }

    // fp32 carried h: hreg[r] = h[row q*4+r][wbase+c]
    float hreg[4] = {0.f, 0.f, 0.f, 0.f};

    for (int t = 0; t <= T_ALL; ++t) {
        __syncthreads();
        const int p = t & 1;

        // A fragments: lane holds h[m=c][k = kt*32+q*8 .. +7]
        short8 ah[4];
        const short* ap = &Abuf[p][c][0];
        #pragma unroll
        for (int kt = 0; kt < 4; ++kt)
            ah[kt] = *reinterpret_cast<const short8*>(ap + kt * 32 + q * 8);

        // fused head on rollout h (Abuf[p] = h_t = hs[t-129] for t >= 129)
        if (wave == 0 && t >= T_OBS + 1) {
            const int s = t - (T_OBS + 1);
            f32x4 acc = {hb, hb, hb, hb};
            #pragma unroll
            for (int kt = 0; kt < 4; ++kt)
                acc = MFMA(ah[kt],
                           *reinterpret_cast<const short8*>(&HeadLds[kt][lane][0]),
                           acc);
            if (c < DIN) {
                #pragma unroll
                for (int r = 0; r < 4; ++r)
                    out[((size_t)(b0 + q * 4 + r) * T_FUT + s) * DIN + c] = acc[r];
            }
        }
        if (t == T_ALL) break;

        if (t == T_OBS) load_phase(cWih, cWhh, cbih, cbhh);  // switch to cell

        // x fragment (5th K-tile): only q==0 lanes hold nonzero k<8
        short8 ax = (short8)0;
        if (q == 0)
            ax = *reinterpret_cast<const short8*>(&Xbuf[t][c][0]);

        // gate MFMAs: 15/wave/step
        f32x4 aR  = {br, br, br, br};
        f32x4 aZ  = {bz, bz, bz, bz};
        f32x4 aNh = {bnh_, bnh_, bnh_, bnh_};
        f32x4 aNi = {bni_, bni_, bni_, bni_};
        #pragma unroll
        for (int kt = 0; kt < 4; ++kt) {
            aR  = MFMA(ah[kt], Wr[kt], aR);
            aZ  = MFMA(ah[kt], Wz[kt], aZ);
            aNh = MFMA(ah[kt], Wn[kt], aNh);
        }
        aR  = MFMA(ax, Wr[4], aR);
        aZ  = MFMA(ax, Wz[4], aZ);
        aNi = MFMA(ax, Wn[4], aNi);

        // elementwise GRU update (lane-local)
        #pragma unroll
        for (int r = 0; r < 4; ++r) {
            float rv = sigm(aR[r]);
            float zv = sigm(aZ[r]);
            float nv = tanh_(aNi[r] + rv * aNh[r]);
            float hn = nv + zv * (hreg[r] - nv);   // (1-z)n + z h
            hreg[r] = hn;
            Abuf[1 - p][q * 4 + r][wbase + c] = f2bf(hn);
        }
    }
}

extern "C" void kernel_launch(void* const* d_in, const int* in_sizes, int n_in,
                              void* d_out, int out_size, void* d_ws, size_t ws_size,
                              hipStream_t stream)
{
    (void)in_sizes; (void)n_in; (void)d_ws; (void)ws_size; (void)out_size;
    gru_tracemodel_kernel<<<dim3(B_TOT / BT), dim3(512), 0, stream>>>(
        (const float*)d_in[0],  (const float*)d_in[1],
        (const float*)d_in[2],  (const float*)d_in[3],
        (const float*)d_in[4],  (const float*)d_in[5],
        (const float*)d_in[6],  (const float*)d_in[7],
        (const float*)d_in[8],  (const float*)d_in[9],
        (const float*)d_in[10], (const float*)d_in[11],
        (float*)d_out);
}

// Round 4
// 408.532 us; speedup vs baseline: 1.3319x; 1.3319x over previous
//
#include <hip/hip_runtime.h>

#define B_TOT 8192
#define T_OBS 128
#define T_FUT 64
#define T_ALL 192
#define DIN 5
#define HD 128
#define BT 16          // batch rows per block (one 16-row MFMA A-tile)
#define LDSTR 136      // Abuf row stride in shorts (pad 8)

typedef __attribute__((ext_vector_type(8))) short short8;
typedef __attribute__((ext_vector_type(4))) float f32x4;

__device__ inline short f2bf(float f) {
    unsigned u = __float_as_uint(f);
    u += 0x7FFFu + ((u >> 16) & 1u);   // round-to-nearest-even
    return (short)(u >> 16);
}

__device__ inline float sigm(float x) {
    return __builtin_amdgcn_rcpf(1.f + __expf(-x));
}
__device__ inline float tanh_(float x) {
    return 1.f - 2.f * __builtin_amdgcn_rcpf(1.f + __expf(2.f * x));
}

__device__ inline f32x4 MFMA(short8 a, short8 b, f32x4 c) {
    return __builtin_amdgcn_mfma_f32_16x16x32_bf16(a, b, c, 0, 0, 0);
}

__device__ inline short8 load_w8(const float* p) {
    float4 a = *reinterpret_cast<const float4*>(p);
    float4 b = *reinterpret_cast<const float4*>(p + 4);
    short8 r;
    r[0] = f2bf(a.x); r[1] = f2bf(a.y); r[2] = f2bf(a.z); r[3] = f2bf(a.w);
    r[4] = f2bf(b.x); r[5] = f2bf(b.y); r[6] = f2bf(b.z); r[7] = f2bf(b.w);
    return r;
}
__device__ inline short8 load_w5(const float* p) {
    short8 r = (short8)0;
    r[0] = f2bf(p[0]); r[1] = f2bf(p[1]); r[2] = f2bf(p[2]);
    r[3] = f2bf(p[3]); r[4] = f2bf(p[4]);
    return r;
}

// 512 threads = 8 waves; wave w owns gate-columns [16w,16w+16) of r/z/n.
// Block owns 16 batch rows; grid = 512 blocks = 2 blocks/CU = 4 waves/SIMD,
// so one block's barrier stall is hidden by the other block's waves.
// __launch_bounds__(512,2): empirically caps VGPR at 128 (R2: 120 VGPR, no
// spill); (512,4) capped at 64 and spilled 163 MB to scratch (R3).
__global__ __launch_bounds__(512, 2)
void gru_tracemodel_kernel(const float* __restrict__ obs, const float* __restrict__ target,
                           const float* __restrict__ eWih, const float* __restrict__ eWhh,
                           const float* __restrict__ ebih, const float* __restrict__ ebhh,
                           const float* __restrict__ cWih, const float* __restrict__ cWhh,
                           const float* __restrict__ cbih, const float* __restrict__ cbhh,
                           const float* __restrict__ headW, const float* __restrict__ headb,
                           float* __restrict__ out)
{
    __shared__ __attribute__((aligned(16))) short Abuf[2][BT][LDSTR];   // 8.5 KB
    __shared__ __attribute__((aligned(16))) short Xbuf[T_ALL][BT][8];   // 48 KB
    __shared__ __attribute__((aligned(16))) short HeadLds[4][64][8];    // 4 KB

    const int tid   = threadIdx.x;
    const int wave  = tid >> 6;    // 0..7
    const int lane  = tid & 63;
    const int q     = lane >> 4;   // quad (A/B k-group, C/D row-group)
    const int c     = lane & 15;   // col-in-tile / A row
    const int b0    = blockIdx.x * BT;
    const int wbase = wave * 16;   // this wave's gate-column slice

    // h0 = 0 (only buffer 0 needed)
    for (int i = tid; i < BT * LDSTR; i += 512) ((short*)Abuf)[i] = 0;

    // stage all x_t as zero-padded bf16 A-rows: Xbuf[t][row][0..4]=x, [5..7]=0
    for (int i = tid; i < T_ALL * BT; i += 512) {
        const int t = i % T_ALL;
        const int r = i / T_ALL;
        const float* src;
        if (t < T_OBS)       src = obs    + ((size_t)(b0 + r) * T_OBS + t) * DIN;
        else if (t == T_OBS) src = obs    + ((size_t)(b0 + r) * T_OBS + (T_OBS - 1)) * DIN;
        else                 src = target + ((size_t)(b0 + r) * T_FUT + (t - T_OBS - 1)) * DIN;
        short* dst = &Xbuf[t][r][0];
        #pragma unroll
        for (int j = 0; j < DIN; ++j) dst[j] = f2bf(src[j]);
        dst[5] = 0; dst[6] = 0; dst[7] = 0;
    }

    // ---- weight fragments (B-operand: lane holds W'[n][k = kt*32+q*8+j]) ----
    short8 Wr[5], Wz[5], Wn[5];
    float  br, bz, bnh_, bni_;

    auto load_phase = [&](const float* Wih, const float* Whh,
                          const float* bih, const float* bhh) {
        const int nr = 0 * HD + wbase + c;
        const int nz = 1 * HD + wbase + c;
        const int nn = 2 * HD + wbase + c;
        #pragma unroll
        for (int kt = 0; kt < 4; ++kt) {
            Wr[kt] = load_w8(Whh + nr * HD + kt * 32 + q * 8);
            Wz[kt] = load_w8(Whh + nz * HD + kt * 32 + q * 8);
            Wn[kt] = load_w8(Whh + nn * HD + kt * 32 + q * 8);
        }
        Wr[4] = (q == 0) ? load_w5(Wih + nr * DIN) : (short8)0;
        Wz[4] = (q == 0) ? load_w5(Wih + nz * DIN) : (short8)0;
        Wn[4] = (q == 0) ? load_w5(Wih + nn * DIN) : (short8)0;
        br   = bih[nr] + bhh[nr];
        bz   = bih[nz] + bhh[nz];
        bnh_ = bhh[nn];
        bni_ = bih[nn];
    };
    load_phase(eWih, eWhh, ebih, ebhh);

    // head B-fragments into LDS (wave 0 only reads them back)
    float hb = 0.f;
    if (wave == 0) {
        #pragma unroll
        for (int kt = 0; kt < 4; ++kt) {
            short8 w = (c < DIN) ? load_w8(headW + c * HD + kt * 32 + q * 8) : (short8)0;
            *reinterpret_cast<short8*>(&HeadLds[kt][lane][0]) = w;
        }
        hb = (c < DIN) ? headb[c] : 0.f;
    }

    // fp32 carried h: hreg[r] = h[row q*4+r][wbase+c]
    float hreg[4] = {0.f, 0.f, 0.f, 0.f};

    for (int t = 0; t <= T_ALL; ++t) {
        __syncthreads();
        const int p = t & 1;

        // A fragments: lane holds h[m=c][k = kt*32+q*8 .. +7]
        short8 ah[4];
        const short* ap = &Abuf[p][c][0];
        #pragma unroll
        for (int kt = 0; kt < 4; ++kt)
            ah[kt] = *reinterpret_cast<const short8*>(ap + kt * 32 + q * 8);

        // fused head on rollout h (Abuf[p] = h_t = hs[t-129] for t >= 129)
        if (wave == 0 && t >= T_OBS + 1) {
            const int s = t - (T_OBS + 1);
            f32x4 acc = {hb, hb, hb, hb};
            #pragma unroll
            for (int kt = 0; kt < 4; ++kt)
                acc = MFMA(ah[kt],
                           *reinterpret_cast<const short8*>(&HeadLds[kt][lane][0]),
                           acc);
            if (c < DIN) {
                #pragma unroll
                for (int r = 0; r < 4; ++r)
                    out[((size_t)(b0 + q * 4 + r) * T_FUT + s) * DIN + c] = acc[r];
            }
        }
        if (t == T_ALL) break;

        if (t == T_OBS) load_phase(cWih, cWhh, cbih, cbhh);  // switch to cell

        // x fragment (5th K-tile): only q==0 lanes hold nonzero k<8
        short8 ax = (short8)0;
        if (q == 0)
            ax = *reinterpret_cast<const short8*>(&Xbuf[t][c][0]);

        // gate MFMAs: 15/wave/step
        f32x4 aR  = {br, br, br, br};
        f32x4 aZ  = {bz, bz, bz, bz};
        f32x4 aNh = {bnh_, bnh_, bnh_, bnh_};
        f32x4 aNi = {bni_, bni_, bni_, bni_};
        #pragma unroll
        for (int kt = 0; kt < 4; ++kt) {
            aR  = MFMA(ah[kt], Wr[kt], aR);
            aZ  = MFMA(ah[kt], Wz[kt], aZ);
            aNh = MFMA(ah[kt], Wn[kt], aNh);
        }
        aR  = MFMA(ax, Wr[4], aR);
        aZ  = MFMA(ax, Wz[4], aZ);
        aNi = MFMA(ax, Wn[4], aNi);

        // elementwise GRU update (lane-local)
        #pragma unroll
        for (int r = 0; r < 4; ++r) {
            float rv = sigm(aR[r]);
            float zv = sigm(aZ[r]);
            float nv = tanh_(aNi[r] + rv * aNh[r]);
            float hn = nv + zv * (hreg[r] - nv);   // (1-z)n + z h
            hreg[r] = hn;
            Abuf[1 - p][q * 4 + r][wbase + c] = f2bf(hn);
        }
    }
}

extern "C" void kernel_launch(void* const* d_in, const int* in_sizes, int n_in,
                              void* d_out, int out_size, void* d_ws, size_t ws_size,
                              hipStream_t stream)
{
    (void)in_sizes; (void)n_in; (void)d_ws; (void)ws_size; (void)out_size;
    gru_tracemodel_kernel<<<dim3(B_TOT / BT), dim3(512), 0, stream>>>(
        (const float*)d_in[0],  (const float*)d_in[1],
        (const float*)d_in[2],  (const float*)d_in[3],
        (const float*)d_in[4],  (const float*)d_in[5],
        (const float*)d_in[6],  (const float*)d_in[7],
        (const float*)d_in[8],  (const float*)d_in[9],
        (const float*)d_in[10], (const float*)d_in[11],
        (float*)d_out);
}